// Round 12
// baseline (92.421 us; speedup 1.0000x reference)
//
#include <hip/hip_runtime.h>

// AdditiveSelfAttentionLayer: B=4, N=1024, D=64, fp32
// out[b,i,d] = sum_j softmax_j( sum_d' tanh(x[b,i,d']+x[b,j,d']) ) * x[b,j,d]
//
// Identities:
//   tanh(s) = 1 - 2/(1+e^{2s});  e_j = sum_d tanh = 64 - 2*rsum
//   a_d = e^{2s_d} = exp2(C*(xi_d+xj_d)), C = 2*log2(e)   (computed in-lane; no E array)
//   PAIR MERGE: 1/(1+a) + 1/(1+b) = (2+p)/(1+p+q),  p=a+b, q=ab  (native v2f pk ops)
//   softmax shift 32: w_j = exp(e_j - 32) = exp2(32*log2e - C*rsum_j)
//
// Round 12 = Round 11 with the inline-asm pin fixed: "+v" on a float4 is a
// tied 128-bit indirect operand (unsupported); pin the 4 scalar components
// instead (each a plain 32-bit tied VGPR). Purpose of the pin: R8/R10 showed
// the allocator remats LDS loads / spills to scratch to chase occupancy;
// volatile asm defs cannot be rematerialized, forcing the x row to stay live.

#define NB 4
#define NN 1024
#define ND 64
#define TJ 64             // j-rows per LDS tile (lane = local j)
#define TI 4              // i-rows per WG = waves per WG
#define NTILES (NN / TJ)  // 16

#if __has_builtin(__builtin_amdgcn_exp2f)
#define EXP2F(x) __builtin_amdgcn_exp2f(x)
#else
#define EXP2F(x) exp2f(x)
#endif
#if __has_builtin(__builtin_amdgcn_rcpf)
#define RCPF(x) __builtin_amdgcn_rcpf(x)
#else
#define RCPF(x) (1.0f / (x))
#endif

static constexpr float C_SCALE = 2.8853900817779268f;   // 2*log2(e)
static constexpr float K_SHIFT = 46.166241308446828f;   // 32*log2(e)

typedef float v2f __attribute__((ext_vector_type(2)));

#define PKFMA(a, b, c) __builtin_elementwise_fma((a), (b), (c))

__device__ __forceinline__ v2f vlo(float4 v) { v2f r; r.x = v.x; r.y = v.y; return r; }
__device__ __forceinline__ v2f vhi(float4 v) { v2f r; r.x = v.z; r.y = v.w; return r; }

__global__ __launch_bounds__(256, 2) void addattn_kernel(const float* __restrict__ x,
                                                         float* __restrict__ out) {
    __shared__ float x_lds[TJ * ND];   // 16 KB, XOR-swizzled at float4 grain

    const int tid   = threadIdx.x;
    const int lane  = tid & 63;
    const int wave  = tid >> 6;
    const int wg    = blockIdx.x;
    const int b     = wg >> 8;                       // 256 WGs per batch
    const int ibase = (wg & 255) * TI;
    // wave-uniform i-row index (forced into SGPR so xi loads become s_loads)
    const int i0    = __builtin_amdgcn_readfirstlane(ibase + wave);

    const float* xb  = x + (size_t)b * NN * ND;
    const float* xip = xb + (size_t)i0 * ND;         // uniform pointer

    // ---- tile-0 loads ----
    float4 px[4];
    {
        const float4* srcx = (const float4*)xb;
        #pragma unroll
        for (int it = 0; it < 4; ++it) px[it] = srcx[it * 256 + tid];
    }
    #pragma unroll
    for (int it = 0; it < 4; ++it) {
        int idx = it * 256 + tid;
        int j   = idx >> 4;         // 16 float4 per row
        int c   = idx & 15;
        *(float4*)&x_lds[j * ND + ((c ^ (j & 15)) << 2)] = px[it];
    }
    __syncthreads();

    v2f acc2[32];                       // out[i0] numerator, d-pairs, in-lane
    #pragma unroll
    for (int k = 0; k < 32; ++k) acc2[k] = (v2f){0.f, 0.f};
    float dn = 0.f;                     // per-lane denominator partial

    const v2f C2 = {C_SCALE, C_SCALE};

    for (int t = 0; t < NTILES; ++t) {
        // ---- prefetch tile t+1's x (16 VGPR; hides under compute) ----
        if (t + 1 < NTILES) {
            const float4* srcx = (const float4*)(xb + (size_t)(t + 1) * TJ * ND);
            #pragma unroll
            for (int it = 0; it < 4; ++it) px[it] = srcx[it * 256 + tid];
        }

        // ---- tanh phase: lane = local j; direct exp2; pair-merged packed rcp ----
        const int key = lane & 15;
        float4 xjs[16];                 // this lane's x row, PINNED for PV
        v2f rse = {0.f, 0.f}, rso = {0.f, 0.f};
        #pragma unroll
        for (int c = 0; c < 16; ++c) {
            float4 xq = *(const float4*)&x_lds[lane * ND + ((c ^ key) << 2)];
            // pin as 4 scalar tied VGPRs (float4 "+v" is unsupported tied-indirect)
            asm volatile("" : "+v"(xq.x), "+v"(xq.y), "+v"(xq.z), "+v"(xq.w));
            xjs[c] = xq;
            float4 xiq = *(const float4*)&xip[c * 4];       // uniform s_load
            v2f Ul = C2 * (vlo(xq) + vlo(xiq));             // C*(xi+xj), d0,d1
            v2f Uh = C2 * (vhi(xq) + vhi(xiq));             // d2,d3
            v2f A, Q;
            A.x = EXP2F(Ul.x); A.y = EXP2F(Ul.y);           // e^{2s}, d0,d1
            Q.x = EXP2F(Uh.x); Q.y = EXP2F(Uh.y);           // e^{2s}, d2,d3
            v2f p = A + Q;
            v2f r = PKFMA(A, Q, p + 1.0f);                  // 1 + p + q
            v2f tt; tt.x = RCPF(r.x); tt.y = RCPF(r.y);
            if (c & 1) rso = PKFMA(p + 2.0f, tt, rso);
            else       rse = PKFMA(p + 2.0f, tt, rse);
        }
        v2f rs = rse + rso;
        float w = EXP2F(fmaf(-C_SCALE, rs.x + rs.y, K_SHIFT)); // = exp(e_j - 32)
        dn += w;
        v2f w2; w2.x = w; w2.y = w;

        // ---- PV phase: acc[d] += w * x[j=lane][d]  (from pinned registers) ----
        #pragma unroll
        for (int c = 0; c < 16; ++c) {
            acc2[2 * c]     = PKFMA(w2, vlo(xjs[c]), acc2[2 * c]);
            acc2[2 * c + 1] = PKFMA(w2, vhi(xjs[c]), acc2[2 * c + 1]);
        }

        // ---- publish prefetched tile ----
        if (t + 1 < NTILES) {
            __syncthreads();   // all waves done reading tile t
            #pragma unroll
            for (int it = 0; it < 4; ++it) {
                int idx = it * 256 + tid;
                int j   = idx >> 4;
                int c   = idx & 15;
                *(float4*)&x_lds[j * ND + ((c ^ (j & 15)) << 2)] = px[it];
            }
            __syncthreads();   // publish tile t+1
        }
    }

    // ---- cross-lane transpose-reduction (round-1/7-verified butterfly) ----
    float* accf = (float*)acc2;
    #pragma unroll
    for (int s = 0; s < 6; ++s) {
        const int half = 32 >> s;
        const int sel  = (lane >> (5 - s)) & 1;
        #pragma unroll
        for (int k = 0; k < half; ++k) {
            float keep = sel ? accf[k + half] : accf[k];
            float send = sel ? accf[k] : accf[k + half];
            float recv = __shfl_xor(send, half, 64);
            accf[k] = keep + recv;
        }
    }
    #pragma unroll
    for (int s = 0; s < 6; ++s) dn += __shfl_xor(dn, 1 << s, 64);

    out[((size_t)b * NN + i0) * ND + lane] = accf[0] * RCPF(dn);
}

extern "C" void kernel_launch(void* const* d_in, const int* in_sizes, int n_in,
                              void* d_out, int out_size, void* d_ws, size_t ws_size,
                              hipStream_t stream) {
    const float* x = (const float*)d_in[0];
    float* out = (float*)d_out;
    dim3 grid(NB * (NN / TI));   // 1024 workgroups
    dim3 block(256);
    addattn_kernel<<<grid, block, 0, stream>>>(x, out);
}